// Round 2
// baseline (905.633 us; speedup 1.0000x reference)
//
#include <hip/hip_runtime.h>
#include <hip/hip_bf16.h>

// GRU-like fused cell: out = (1-z)*tanh(i_n + r*h_n) + z*e
//   r = sigmoid(W_ih_r@m + W_hh_r@e), z = sigmoid(...z...), i_n = W_ih_n@m, h_n = W_hh_n@e
// B=8, H=512, N=8192. bf16 MFMA (16x16x32), fp32 accumulate, fused epilogue.
//
// R1 -> R2: __launch_bounds__(512,2) capped VGPRs at 128 while the kernel needs ~230
// (acc 128 + bv 32 + frags 40 + addr) -> accumulator spill to scratch = 1.38 GB of
// bogus HBM writes, MfmaUtil 8.8%. LDS (114KB) forces 1 WG/CU anyway, so cap to
// (512,1): 256-VGPR budget + unified AGPR overflow, zero spill.

#define HH 512
#define NBATCH 8
#define NN 8192
#define BM 64            // h rows per workgroup
#define BN 256           // n cols per workgroup
#define BK 64            // k per step
#define NSTEPS 16        // K=1024 (concat m|e) / BK
#define THREADS 512
#define A_BYTES (192 * BK * 2)          // 3 gate-row-blocks x 64 rows x BK bf16 = 24576
#define B_BYTES (BN * BK * 2)           // 32768
#define BUF_BYTES (A_BYTES + B_BYTES)   // 57344, x2 buffers = 114688 LDS

typedef __attribute__((ext_vector_type(8))) short short8;  // 8 bf16 = 4 VGPR (MFMA A/B frag)
typedef __attribute__((ext_vector_type(4))) float f32x4;   // MFMA C/D frag

__device__ __forceinline__ unsigned cvt_pk_bf16(float a, float b) {
  unsigned r;
  asm("v_cvt_pk_bf16_f32 %0, %1, %2" : "=v"(r) : "v"(a), "v"(b));
  return r;
}

__device__ __forceinline__ void gload_lds16(const void* g, void* l) {
  __builtin_amdgcn_global_load_lds(
      (__attribute__((address_space(1))) void*)(g),
      (__attribute__((address_space(3))) void*)(l), 16, 0, 0);
}

#define MFMA16(a_, b_, c_) __builtin_amdgcn_mfma_f32_16x16x32_bf16((a_), (b_), (c_), 0, 0, 0)

// ---------------- weight pre-pack ----------------
// ws image: for (ht 0..7, s 0..15): 192x64 bf16 block, laid out exactly as the main
// kernel's A LDS buffer (row-major 128B rows, XOR-swizzled), so global_load_lds streams
// it linearly.  A rows: ra in [0,192): gate g = ra>>6, h = ht*64 + (ra&63).
// k (global, 0..1023): <512 -> W_ih, >=512 -> W_hh.
__global__ void prepack_w(const float* __restrict__ W_ih, const float* __restrict__ W_hh,
                          __hip_bfloat16* __restrict__ ws) {
  int t = blockIdx.x * 256 + threadIdx.x;           // 0 .. 8*16*12288-1
  int blk = t / 12288;                              // ht*16 + s
  int e = t % 12288;
  int ra = e >> 6;                                  // 0..191
  int kk = (e & 63) ^ ((ra & 7) << 3);              // inverse of read-side XOR swizzle
  int gate = ra >> 6;
  int h = (blk >> 4) * 64 + (ra & 63);
  int row = gate * HH + h;                          // 0..1535
  int kg = (blk & 15) * 64 + kk;                    // 0..1023
  float v = (kg < 512) ? W_ih[row * 512 + kg] : W_hh[row * 512 + (kg - 512)];
  ws[t] = __float2bfloat16(v);
}

// ---------------- main fused kernel ----------------
__global__ __launch_bounds__(THREADS, 1)
void gru_main(const float* __restrict__ e_wv, const float* __restrict__ m_wv,
              const __hip_bfloat16* __restrict__ wimg, float* __restrict__ out) {
  extern __shared__ char smem[];
  const int tid  = threadIdx.x;
  const int lane = tid & 63;
  const int wave = tid >> 6;
  const int wm = wave >> 2;        // 0..1 : 32-row half of the 64-h tile
  const int wn = wave & 3;         // 0..3 : 64-col quarter of the 256-n tile

  // XCD swizzle: consecutive hardware blocks round-robin XCDs; give each XCD a
  // contiguous chunk of (b, nt, ht) work with ht fastest so same-X-slab tiles share L2.
  const int wg  = blockIdx.x;
  const int swz = (wg & 7) * 256 + (wg >> 3);   // 2048 wgs, 8 | 2048
  const int ht  = swz & 7;
  const int nt  = (swz >> 3) & 31;
  const int b   = swz >> 8;

  // X staging decomposition: thread owns a 4k x 8n block
  const int k0  = (tid & 15) << 2;   // 0..60
  const int n0s = (tid >> 4) << 3;   // 0..248

  const size_t batch_off = (size_t)b * HH * NN;
  const float* xm = m_wv + batch_off + (size_t)k0 * NN + nt * BN + n0s;
  const float* xe = e_wv + batch_off + (size_t)k0 * NN + nt * BN + n0s;
  const char*  wimg_c = (const char*)wimg + (size_t)ht * NSTEPS * A_BYTES + tid * 16;

  f32x4 acc_r[2][4]  = {};
  f32x4 acc_z[2][4]  = {};
  f32x4 acc_in[2][4] = {};
  f32x4 acc_hn[2][4] = {};
  f32x4 bv[4][2];   // staged X f32 (4 rows x 8 cols)

  auto stage_issue = [&](int s, int buf) {
    // A: async global->LDS (pre-swizzled image, linear copy)
    const char* gA = wimg_c + (size_t)s * A_BYTES;
    char* lA = smem + buf * BUF_BYTES + tid * 16;
    gload_lds16(gA,          lA);
    gload_lds16(gA + 8192,   lA + 8192);
    gload_lds16(gA + 16384,  lA + 16384);
    // X: global -> regs (f32)
    const float* xs = (s < 8 ? xm : xe) + (size_t)(s & 7) * (64 * NN);
#pragma unroll
    for (int i = 0; i < 4; ++i) {
      bv[i][0] = *(const f32x4*)(xs + (size_t)i * NN);
      bv[i][1] = *(const f32x4*)(xs + (size_t)i * NN + 4);
    }
  };

  auto stage_write = [&](int buf) {
    // regs -> LDS B tile, layout [n][k] bf16, 128B rows, byte ^= (n&7)<<4
    char* Bb = smem + buf * BUF_BYTES + A_BYTES;
#pragma unroll
    for (int j = 0; j < 8; ++j) {
      unsigned lo = cvt_pk_bf16(bv[0][j >> 2][j & 3], bv[1][j >> 2][j & 3]);
      unsigned hi = cvt_pk_bf16(bv[2][j >> 2][j & 3], bv[3][j >> 2][j & 3]);
      int off = (n0s + j) * 128 + ((k0 * 2) ^ (j << 4));   // (n&7)==j here
      *(uint2*)(Bb + off) = make_uint2(lo, hi);
    }
  };

  auto compute = [&](int buf, bool first) {
    const char* Ab   = smem + buf * BUF_BYTES;
    const char* Bbuf = Ab + A_BYTES;
#pragma unroll
    for (int kb2 = 0; kb2 < 2; ++kb2) {
      const int ke2 = (kb2 * 32 + ((lane >> 4) << 3)) * 2;  // k byte offset within row
      short8 af[3][2];
      short8 bfr[4];
#pragma unroll
      for (int g = 0; g < 3; ++g)
#pragma unroll
        for (int mi = 0; mi < 2; ++mi) {
          int ra = g * 64 + wm * 32 + mi * 16 + (lane & 15);
          af[g][mi] = *(const short8*)(Ab + ra * 128 + (ke2 ^ ((ra & 7) << 4)));
        }
#pragma unroll
      for (int ni = 0; ni < 4; ++ni) {
        int n = wn * 64 + ni * 16 + (lane & 15);
        bfr[ni] = *(const short8*)(Bbuf + n * 128 + (ke2 ^ ((n & 7) << 4)));
      }
#pragma unroll
      for (int mi = 0; mi < 2; ++mi)
#pragma unroll
        for (int ni = 0; ni < 4; ++ni) {
          acc_r[mi][ni] = MFMA16(af[0][mi], bfr[ni], acc_r[mi][ni]);
          acc_z[mi][ni] = MFMA16(af[1][mi], bfr[ni], acc_z[mi][ni]);
          if (first) acc_in[mi][ni] = MFMA16(af[2][mi], bfr[ni], acc_in[mi][ni]);
          else       acc_hn[mi][ni] = MFMA16(af[2][mi], bfr[ni], acc_hn[mi][ni]);
        }
    }
  };

  // prologue
  stage_issue(0, 0);
  stage_write(0);
  __syncthreads();

  for (int s = 0; s < NSTEPS; ++s) {
    const int cur = s & 1;
    if (s < NSTEPS - 1) stage_issue(s + 1, cur ^ 1);   // overlaps with compute below
    if (s < 8) compute(cur, true);
    else       compute(cur, false);
    if (s < NSTEPS - 1) stage_write(cur ^ 1);
    __syncthreads();
  }

  // epilogue: gates + blend, read e (f32), write out (f32)
  const size_t obase = batch_off + (size_t)(ht * 64 + wm * 32) * NN + nt * BN + wn * 64;
  const float* ep = e_wv + obase;
  float* op = out + obase;
  const int rsub = (lane >> 4) << 2;
  const int csub = lane & 15;
#pragma unroll
  for (int mi = 0; mi < 2; ++mi)
#pragma unroll
    for (int ni = 0; ni < 4; ++ni) {
#pragma unroll
      for (int r = 0; r < 4; ++r) {
        size_t idx = (size_t)(mi * 16 + rsub + r) * NN + ni * 16 + csub;
        float pr  = acc_r[mi][ni][r];
        float pz  = acc_z[mi][ni][r];
        float vin = acc_in[mi][ni][r];
        float vhn = acc_hn[mi][ni][r];
        float rr  = 1.f / (1.f + __expf(-pr));
        float zz  = 1.f / (1.f + __expf(-pz));
        float ex  = __expf(2.f * (vin + rr * vhn));
        float nn2 = 1.f - 2.f / (ex + 1.f);      // tanh, inf-safe
        float ev  = ep[idx];
        op[idx] = (1.f - zz) * nn2 + zz * ev;
      }
    }
}

extern "C" void kernel_launch(void* const* d_in, const int* in_sizes, int n_in,
                              void* d_out, int out_size, void* d_ws, size_t ws_size,
                              hipStream_t stream) {
  const float* e_wv = (const float*)d_in[0];
  const float* m_wv = (const float*)d_in[1];
  const float* W_ih = (const float*)d_in[2];
  const float* W_hh = (const float*)d_in[3];
  float* out = (float*)d_out;
  __hip_bfloat16* wimg = (__hip_bfloat16*)d_ws;   // 3 MiB weight image

  // allow >64KB dynamic LDS (no-op if already allowed); not a stream op -> capture-safe
  (void)hipFuncSetAttribute((const void*)gru_main,
                            hipFuncAttributeMaxDynamicSharedMemorySize, BUF_BYTES * 2);

  prepack_w<<<(NBATCH * NSTEPS * 12288) / 256, 256, 0, stream>>>(W_ih, W_hh, wimg);
  gru_main<<<NBATCH * 8 * 32, THREADS, BUF_BYTES * 2, stream>>>(e_wv, m_wv, wimg, out);
}

// Round 3
// 425.500 us; speedup vs baseline: 2.1284x; 2.1284x over previous
//
#include <hip/hip_runtime.h>
#include <hip/hip_bf16.h>

// GRU-like fused cell: out = (1-z)*tanh(i_n + r*h_n) + z*e
//   r = sigmoid(W_ih_r@m + W_hh_r@e), z = sigmoid(...), i_n = W_ih_n@m, h_n = W_hh_n@e
// B=8, H=512, N=8192. bf16 MFMA 16x16x32, fp32 acc, fused epilogue.
//
// R2 -> R3: 512-thr WG => 8 waves MUST co-reside => hard 256 unified regs/wave.
// Previous demand ~280 -> ~25-reg spill rewritten every K-step = 1.25 GB scratch
// writes (the WRITE_SIZE smoking gun). This version cuts demand to ~210:
//   - A-fragments loaded per-gate (live range 8 regs, was 24)
//   - #pragma unroll 1 main loop (no cross-iteration pipelining blowup)
//   - uniform branch for in/hn accumulator target (no runtime-indexed arrays)

#define HH 512
#define NBATCH 8
#define NN 8192
#define BN 256
#define BK 64
#define NSTEPS 16
#define THREADS 512
#define A_BYTES (192 * BK * 2)          // 24576
#define B_BYTES (BN * BK * 2)           // 32768
#define BUF_BYTES (A_BYTES + B_BYTES)   // 57344 x2 = 114688 LDS

typedef __attribute__((ext_vector_type(8))) short short8;
typedef __attribute__((ext_vector_type(4))) float f32x4;

__device__ __forceinline__ unsigned cvt_pk_bf16(float a, float b) {
  unsigned r;
  asm("v_cvt_pk_bf16_f32 %0, %1, %2" : "=v"(r) : "v"(a), "v"(b));
  return r;
}

__device__ __forceinline__ void gload_lds16(const void* g, void* l) {
  __builtin_amdgcn_global_load_lds(
      (__attribute__((address_space(1))) void*)(g),
      (__attribute__((address_space(3))) void*)(l), 16, 0, 0);
}

#define MFMA16(a_, b_, c_) __builtin_amdgcn_mfma_f32_16x16x32_bf16((a_), (b_), (c_), 0, 0, 0)

// ---------------- weight pre-pack (unchanged, verified in R1/R2) ----------------
__global__ void prepack_w(const float* __restrict__ W_ih, const float* __restrict__ W_hh,
                          __hip_bfloat16* __restrict__ ws) {
  int t = blockIdx.x * 256 + threadIdx.x;
  int blk = t / 12288;                              // ht*16 + s
  int e = t % 12288;
  int ra = e >> 6;                                  // 0..191
  int kk = (e & 63) ^ ((ra & 7) << 3);              // inverse of read-side XOR swizzle
  int gate = ra >> 6;
  int h = (blk >> 4) * 64 + (ra & 63);
  int row = gate * HH + h;
  int kg = (blk & 15) * 64 + kk;
  float v = (kg < 512) ? W_ih[row * 512 + kg] : W_hh[row * 512 + (kg - 512)];
  ws[t] = __float2bfloat16(v);
}

// ---------------- main fused kernel ----------------
__global__ __launch_bounds__(THREADS, 2)
void gru_main(const float* __restrict__ e_wv, const float* __restrict__ m_wv,
              const __hip_bfloat16* __restrict__ wimg, float* __restrict__ out) {
  extern __shared__ char smem[];
  const int tid  = threadIdx.x;
  const int lane = tid & 63;
  const int wave = tid >> 6;
  const int wm = wave >> 2;        // 0..1 : 32-row half of 64-h tile
  const int wn = wave & 3;         // 0..3 : 64-col quarter of 256-n tile

  // XCD swizzle: ht fastest within an XCD so the 8 ht-sharers of one X slab
  // run concurrently on the same XCD (L2 hit / in-flight coalesce).
  const int wg  = blockIdx.x;
  const int swz = (wg & 7) * 256 + (wg >> 3);
  const int ht  = swz & 7;
  const int nt  = (swz >> 3) & 31;
  const int b   = swz >> 8;

  const int k0  = (tid & 15) << 2;   // 0..60  (4 k-rows per thread)
  const int n0s = (tid >> 4) << 3;   // 0..248 (8 n-cols per thread)

  const size_t batch_off = (size_t)b * HH * NN;
  const float* xm = m_wv + batch_off + (size_t)k0 * NN + nt * BN + n0s;
  const float* xe = e_wv + batch_off + (size_t)k0 * NN + nt * BN + n0s;
  const char*  wA = (const char*)wimg + (size_t)ht * NSTEPS * A_BYTES + tid * 16;

  f32x4 acc_r[2][4]  = {};
  f32x4 acc_z[2][4]  = {};
  f32x4 acc_in[2][4] = {};
  f32x4 acc_hn[2][4] = {};
  f32x4 bv[4][2];   // staged X f32: 4 k-rows x 8 n-cols

  auto issue_A = [&](const char* gA, char* bufp) {
    char* lA = bufp + tid * 16;
    gload_lds16(gA,         lA);
    gload_lds16(gA + 8192,  lA + 8192);
    gload_lds16(gA + 16384, lA + 16384);
  };
  auto issue_X = [&](const float* xs) {
#pragma unroll
    for (int i = 0; i < 4; ++i) {
      bv[i][0] = *(const f32x4*)(xs + (size_t)i * NN);
      bv[i][1] = *(const f32x4*)(xs + (size_t)i * NN + 4);
    }
  };
  auto write_X = [&](char* bufp) {
    char* Bb = bufp + A_BYTES;
#pragma unroll
    for (int j = 0; j < 8; ++j) {
      unsigned lo = cvt_pk_bf16(bv[0][j >> 2][j & 3], bv[1][j >> 2][j & 3]);
      unsigned hi = cvt_pk_bf16(bv[2][j >> 2][j & 3], bv[3][j >> 2][j & 3]);
      int off = (n0s + j) * 128 + ((k0 * 2) ^ (j << 4));   // (n&7)==j
      *(uint2*)(Bb + off) = make_uint2(lo, hi);
    }
  };

  // prologue: stage tile 0
  issue_A(wA, smem);
  issue_X(xm);
  write_X(smem);
  __syncthreads();

#pragma unroll 1
  for (int s = 0; s < NSTEPS; ++s) {
    char* cbuf = smem + (s & 1) * BUF_BYTES;
    char* nbuf = smem + ((s + 1) & 1) * BUF_BYTES;
    if (s < NSTEPS - 1) {
      issue_A(wA + (size_t)(s + 1) * A_BYTES, nbuf);
      const float* xs = ((s + 1) < 8 ? xm : xe) + (size_t)((s + 1) & 7) * (64 * NN);
      issue_X(xs);   // in flight across compute; consumed in write_X below
    }

    const char* Ab   = cbuf;
    const char* Bbuf = cbuf + A_BYTES;
    const bool firstHalf = (s < 8);
#pragma unroll
    for (int kb2 = 0; kb2 < 2; ++kb2) {
      const int ke2 = kb2 * 64 + ((lane >> 4) << 4);  // k byte offset within 128B row
      short8 bfr[4];
#pragma unroll
      for (int ni = 0; ni < 4; ++ni) {
        int n = wn * 64 + ni * 16 + (lane & 15);
        bfr[ni] = *(const short8*)(Bbuf + n * 128 + (ke2 ^ ((n & 7) << 4)));
      }
      // gate 0 (r): load 2 A-frags, fire 8 MFMAs, frags die
      {
        int ra0 = 0 * 64 + wm * 32 + (lane & 15);
        short8 a0 = *(const short8*)(Ab + ra0 * 128 + (ke2 ^ ((ra0 & 7) << 4)));
        int ra1 = ra0 + 16;
        short8 a1 = *(const short8*)(Ab + ra1 * 128 + (ke2 ^ ((ra1 & 7) << 4)));
#pragma unroll
        for (int ni = 0; ni < 4; ++ni) {
          acc_r[0][ni] = MFMA16(a0, bfr[ni], acc_r[0][ni]);
          acc_r[1][ni] = MFMA16(a1, bfr[ni], acc_r[1][ni]);
        }
      }
      // gate 1 (z)
      {
        int ra0 = 1 * 64 + wm * 32 + (lane & 15);
        short8 a0 = *(const short8*)(Ab + ra0 * 128 + (ke2 ^ ((ra0 & 7) << 4)));
        int ra1 = ra0 + 16;
        short8 a1 = *(const short8*)(Ab + ra1 * 128 + (ke2 ^ ((ra1 & 7) << 4)));
#pragma unroll
        for (int ni = 0; ni < 4; ++ni) {
          acc_z[0][ni] = MFMA16(a0, bfr[ni], acc_z[0][ni]);
          acc_z[1][ni] = MFMA16(a1, bfr[ni], acc_z[1][ni]);
        }
      }
      // gate 2 (n): target acc_in during m-phase, acc_hn during e-phase (uniform branch)
      {
        int ra0 = 2 * 64 + wm * 32 + (lane & 15);
        short8 a0 = *(const short8*)(Ab + ra0 * 128 + (ke2 ^ ((ra0 & 7) << 4)));
        int ra1 = ra0 + 16;
        short8 a1 = *(const short8*)(Ab + ra1 * 128 + (ke2 ^ ((ra1 & 7) << 4)));
        if (firstHalf) {
#pragma unroll
          for (int ni = 0; ni < 4; ++ni) {
            acc_in[0][ni] = MFMA16(a0, bfr[ni], acc_in[0][ni]);
            acc_in[1][ni] = MFMA16(a1, bfr[ni], acc_in[1][ni]);
          }
        } else {
#pragma unroll
          for (int ni = 0; ni < 4; ++ni) {
            acc_hn[0][ni] = MFMA16(a0, bfr[ni], acc_hn[0][ni]);
            acc_hn[1][ni] = MFMA16(a1, bfr[ni], acc_hn[1][ni]);
          }
        }
      }
    }

    if (s < NSTEPS - 1) write_X(nbuf);   // X latency hidden under compute above
    __syncthreads();
  }

  // epilogue: gates + blend (unchanged from verified R1)
  const size_t obase = batch_off + (size_t)(ht * 64 + wm * 32) * NN + nt * BN + wn * 64;
  const float* ep = e_wv + obase;
  float* op = out + obase;
  const int rsub = (lane >> 4) << 2;
  const int csub = lane & 15;
#pragma unroll
  for (int mi = 0; mi < 2; ++mi)
#pragma unroll
    for (int ni = 0; ni < 4; ++ni) {
#pragma unroll
      for (int r = 0; r < 4; ++r) {
        size_t idx = (size_t)(mi * 16 + rsub + r) * NN + ni * 16 + csub;
        float pr  = acc_r[mi][ni][r];
        float pz  = acc_z[mi][ni][r];
        float vin = acc_in[mi][ni][r];
        float vhn = acc_hn[mi][ni][r];
        float rr  = 1.f / (1.f + __expf(-pr));
        float zz  = 1.f / (1.f + __expf(-pz));
        float ex  = __expf(2.f * (vin + rr * vhn));
        float nn2 = 1.f - 2.f / (ex + 1.f);      // tanh, inf-safe
        float ev  = ep[idx];
        op[idx] = (1.f - zz) * nn2 + zz * ev;
      }
    }
}

extern "C" void kernel_launch(void* const* d_in, const int* in_sizes, int n_in,
                              void* d_out, int out_size, void* d_ws, size_t ws_size,
                              hipStream_t stream) {
  const float* e_wv = (const float*)d_in[0];
  const float* m_wv = (const float*)d_in[1];
  const float* W_ih = (const float*)d_in[2];
  const float* W_hh = (const float*)d_in[3];
  float* out = (float*)d_out;
  __hip_bfloat16* wimg = (__hip_bfloat16*)d_ws;   // 3 MiB weight image

  (void)hipFuncSetAttribute((const void*)gru_main,
                            hipFuncAttributeMaxDynamicSharedMemorySize, BUF_BYTES * 2);

  prepack_w<<<(NBATCH * NSTEPS * 12288) / 256, 256, 0, stream>>>(W_ih, W_hh, wimg);
  gru_main<<<NBATCH * 8 * 32, THREADS, BUF_BYTES * 2, stream>>>(e_wv, m_wv, wimg, out);
}